// Round 1
// baseline (238.370 us; speedup 1.0000x reference)
//
#include <hip/hip_runtime.h>
#include <hip/hip_bf16.h>

typedef __attribute__((ext_vector_type(8))) __bf16 bf16x8;
typedef __attribute__((ext_vector_type(4))) float f32x4;

#define BATCH 16
#define CH    64
#define NN    65536
#define KCHUNK 2048
#define BK    256
#define NB    256

__device__ __forceinline__ unsigned short f2bf(float f) {
  unsigned int u = __float_as_uint(f);
  u += 0x7FFFu + ((u >> 16) & 1u);   // RNE
  return (unsigned short)(u >> 16);
}

__global__ __launch_bounds__(256) void k_zero(float* p) {
  p[blockIdx.x * 256 + threadIdx.x] = 0.0f;
}

// Pass 1: energy[b,i,j] = sum_n x[b,i,n] x[b,j,n], split-K with fp32 atomics.
// bf16 MFMA 16x16x32; LDS tile [64][256] bf16 with XOR swizzle (G4).
__global__ __launch_bounds__(256) void k_energy(const float* __restrict__ x,
                                                float* __restrict__ energy) {
  const int chunk = blockIdx.x;          // 0..31
  const int b = blockIdx.y;              // 0..15
  const int t = threadIdx.x;
  const int w = t >> 6;                  // wave 0..3
  const int lane = t & 63;
  const int fr = lane & 15;
  const int grp = lane >> 4;

  __shared__ __align__(16) unsigned short xs[CH * BK];  // 32 KiB, swizzled bf16

  f32x4 acc[4] = {};

  const float* xb = x + (size_t)b * CH * NN;
  const int k0 = chunk * KCHUNK;

  for (int s = 0; s < KCHUNK / BK; ++s) {
    const int kb = k0 + s * BK;
    __syncthreads();  // previous-iter reads done before overwrite
    #pragma unroll
    for (int it = 0; it < 16; ++it) {
      const int flat = it * 256 + t;     // 0..4095 float4s
      const int row = flat >> 6;         // 0..63
      const int c4 = flat & 63;
      const float4 v = *reinterpret_cast<const float4*>(xb + (size_t)row * NN + kb + c4 * 4);
      ushort4 pk;
      pk.x = f2bf(v.x); pk.y = f2bf(v.y); pk.z = f2bf(v.z); pk.w = f2bf(v.w);
      int byte = (row * BK + c4 * 4) * 2;
      byte ^= (row & 7) << 4;            // swizzle (8B-granule safe: no bit3)
      *reinterpret_cast<ushort4*>(reinterpret_cast<char*>(xs) + byte) = pk;
    }
    __syncthreads();
    const char* xsb = reinterpret_cast<const char*>(xs);
    #pragma unroll
    for (int kk = 0; kk < BK / 32; ++kk) {
      const int arow = w * 16 + fr;
      int aoff = (arow * BK + kk * 32 + grp * 8) * 2;
      aoff ^= (arow & 7) << 4;
      const bf16x8 af = *reinterpret_cast<const bf16x8*>(xsb + aoff);
      #pragma unroll
      for (int tt = 0; tt < 4; ++tt) {
        const int brow = tt * 16 + fr;
        int boff = (brow * BK + kk * 32 + grp * 8) * 2;
        boff ^= (brow & 7) << 4;
        const bf16x8 bf = *reinterpret_cast<const bf16x8*>(xsb + boff);
        acc[tt] = __builtin_amdgcn_mfma_f32_16x16x32_bf16(af, bf, acc[tt], 0, 0, 0);
      }
    }
  }
  // C/D layout (m89-verified): col = lane&15, row = (lane>>4)*4 + reg
  #pragma unroll
  for (int tt = 0; tt < 4; ++tt) {
    #pragma unroll
    for (int r = 0; r < 4; ++r) {
      const int i = w * 16 + grp * 4 + r;
      const int j = tt * 16 + fr;
      atomicAdd(&energy[((size_t)b * CH + i) * CH + j], acc[tt][r]);
    }
  }
}

// Pass 2: attention = softmax(rowmax - energy) over last dim.
// softmax(rowmax - e)[j] = exp(minE - e[j]) / sum  (rowmax cancels).
// Stored TRANSPOSED: attn_t[b][j][i] for float4-friendly pass-3 reads.
__global__ __launch_bounds__(64) void k_softmax(const float* __restrict__ energy,
                                                float* __restrict__ attn_t) {
  const int b = blockIdx.x;
  const int i = threadIdx.x;
  const float* e = energy + ((size_t)b * CH + i) * CH;
  float ev[CH];
  float mn = 3.402823466e38f;
  #pragma unroll
  for (int j = 0; j < CH; ++j) { ev[j] = e[j]; mn = fminf(mn, ev[j]); }
  float sum = 0.0f;
  #pragma unroll
  for (int j = 0; j < CH; ++j) { ev[j] = __expf(mn - ev[j]); sum += ev[j]; }
  const float inv = 1.0f / sum;
  #pragma unroll
  for (int j = 0; j < CH; ++j) attn_t[((size_t)b * CH + j) * CH + i] = ev[j] * inv;
}

// Pass 3: out[b,i,n] = gamma * sum_j attn[i,j] x[b,j,n] + x[b,i,n], all fp32.
// Wave w owns rows i in [16w,16w+16), lane L owns n-columns [n0+4L, n0+4L+4).
__global__ __launch_bounds__(256) void k_out(const float* __restrict__ x,
                                             const float* __restrict__ attn_t,
                                             const float* __restrict__ gamma,
                                             float* __restrict__ out) {
  const int b = blockIdx.y;
  const int n0 = blockIdx.x * NB;
  const int t = threadIdx.x;
  const int w = t >> 6;
  const int lane = t & 63;

  __shared__ __align__(16) float xsh[CH * NB];  // 64 KiB
  __shared__ __align__(16) float ash[CH * CH];  // 16 KiB (attn_t tile)

  const float* xb = x + (size_t)b * CH * NN;
  #pragma unroll
  for (int it = 0; it < 16; ++it) {
    const int flat = it * 256 + t;
    const int row = flat >> 6;
    const int c4 = flat & 63;
    *reinterpret_cast<f32x4*>(&xsh[row * NB + c4 * 4]) =
        *reinterpret_cast<const f32x4*>(xb + (size_t)row * NN + n0 + c4 * 4);
  }
  #pragma unroll
  for (int it = 0; it < 4; ++it) {
    const int flat = it * 256 + t;  // 0..1023 float4s
    *reinterpret_cast<f32x4*>(&ash[flat * 4]) =
        *reinterpret_cast<const f32x4*>(attn_t + (size_t)b * CH * CH + flat * 4);
  }
  const float g = gamma[0];
  __syncthreads();

  f32x4 acc[16] = {};
  #pragma unroll 4
  for (int j = 0; j < CH; ++j) {
    const f32x4 xv = *reinterpret_cast<const f32x4*>(&xsh[j * NB + lane * 4]);
    #pragma unroll
    for (int q = 0; q < 4; ++q) {
      // ash[j][16w+4q .. +3] — wave-uniform broadcast read
      const f32x4 av = *reinterpret_cast<const f32x4*>(&ash[j * CH + w * 16 + q * 4]);
      acc[q * 4 + 0] += av[0] * xv;
      acc[q * 4 + 1] += av[1] * xv;
      acc[q * 4 + 2] += av[2] * xv;
      acc[q * 4 + 3] += av[3] * xv;
    }
  }
  float* ob = out + (size_t)b * CH * NN;
  #pragma unroll
  for (int r = 0; r < 16; ++r) {
    const int i = w * 16 + r;
    const f32x4 xv = *reinterpret_cast<const f32x4*>(&xsh[i * NB + lane * 4]);
    const f32x4 o = g * acc[r] + xv;  // exact fp32 epilogue
    *reinterpret_cast<f32x4*>(ob + (size_t)i * NN + n0 + lane * 4) = o;
  }
}

extern "C" void kernel_launch(void* const* d_in, const int* in_sizes, int n_in,
                              void* d_out, int out_size, void* d_ws, size_t ws_size,
                              hipStream_t stream) {
  const float* x = (const float*)d_in[0];
  const float* gamma = (const float*)d_in[1];
  float* out = (float*)d_out;
  float* energy = (float*)d_ws;                       // 16*64*64 fp32 = 256 KiB
  float* attn_t = energy + (size_t)BATCH * CH * CH;   // another 256 KiB

  k_zero<<<dim3((BATCH * CH * CH) / 256), 256, 0, stream>>>(energy);
  k_energy<<<dim3(NN / KCHUNK, BATCH), 256, 0, stream>>>(x, energy);
  k_softmax<<<dim3(BATCH), 64, 0, stream>>>(energy, attn_t);
  k_out<<<dim3(NN / NB, BATCH), 256, 0, stream>>>(x, attn_t, gamma, out);
}

// Round 2
// 199.892 us; speedup vs baseline: 1.1925x; 1.1925x over previous
//
#include <hip/hip_runtime.h>
#include <hip/hip_bf16.h>

typedef __attribute__((ext_vector_type(8))) __bf16 bf16x8;
typedef __attribute__((ext_vector_type(4))) float f32x4;

#define BATCH 16
#define CH    64
#define NN    65536
#define BK    256
#define NB    256
#define KC_P  512               // K chunk per block, partial-store path
#define NC_P  (NN / KC_P)       // 128 chunks
#define KC_A  2048              // atomic fallback (round-1 proven)
#define NC_A  (NN / KC_A)       // 32 chunks

__device__ __forceinline__ unsigned short f2bf(float f) {
  unsigned int u = __float_as_uint(f);
  u += 0x7FFFu + ((u >> 16) & 1u);   // RNE
  return (unsigned short)(u >> 16);
}

__global__ __launch_bounds__(256) void k_zero(float* p) {
  p[blockIdx.x * 256 + threadIdx.x] = 0.0f;
}

// Pass 1: energy[b,i,j] = sum_n x[b,i,n] x[b,j,n], split-K.
// bf16 MFMA 16x16x32; LDS tile [64][256] bf16 with XOR swizzle (G4).
// ATOMIC=false: block writes its private 64x64 partial (no contention).
template <int KCHUNK, bool ATOMIC>
__global__ __launch_bounds__(256) void k_energy(const float* __restrict__ x,
                                                float* __restrict__ dst) {
  const int chunk = blockIdx.x;          // 0..NN/KCHUNK-1
  const int b = blockIdx.y;              // 0..15
  const int t = threadIdx.x;
  const int w = t >> 6;                  // wave 0..3
  const int lane = t & 63;
  const int fr = lane & 15;
  const int grp = lane >> 4;

  __shared__ __align__(16) unsigned short xs[CH * BK];  // 32 KiB, swizzled bf16

  f32x4 acc[4] = {};

  const float* xb = x + (size_t)b * CH * NN;
  const int k0 = chunk * KCHUNK;

  for (int s = 0; s < KCHUNK / BK; ++s) {
    const int kb = k0 + s * BK;
    __syncthreads();  // previous-iter reads done before overwrite
    #pragma unroll
    for (int it = 0; it < 16; ++it) {
      const int flat = it * 256 + t;     // 0..4095 float4s
      const int row = flat >> 6;         // 0..63
      const int c4 = flat & 63;
      const float4 v = *reinterpret_cast<const float4*>(xb + (size_t)row * NN + kb + c4 * 4);
      ushort4 pk;
      pk.x = f2bf(v.x); pk.y = f2bf(v.y); pk.z = f2bf(v.z); pk.w = f2bf(v.w);
      int byte = (row * BK + c4 * 4) * 2;
      byte ^= (row & 7) << 4;            // swizzle (8B-granule safe: no bit3)
      *reinterpret_cast<ushort4*>(reinterpret_cast<char*>(xs) + byte) = pk;
    }
    __syncthreads();
    const char* xsb = reinterpret_cast<const char*>(xs);
    #pragma unroll
    for (int kk = 0; kk < BK / 32; ++kk) {
      const int arow = w * 16 + fr;
      int aoff = (arow * BK + kk * 32 + grp * 8) * 2;
      aoff ^= (arow & 7) << 4;
      const bf16x8 af = *reinterpret_cast<const bf16x8*>(xsb + aoff);
      #pragma unroll
      for (int tt = 0; tt < 4; ++tt) {
        const int brow = tt * 16 + fr;
        int boff = (brow * BK + kk * 32 + grp * 8) * 2;
        boff ^= (brow & 7) << 4;
        const bf16x8 bf = *reinterpret_cast<const bf16x8*>(xsb + boff);
        acc[tt] = __builtin_amdgcn_mfma_f32_16x16x32_bf16(af, bf, acc[tt], 0, 0, 0);
      }
    }
  }
  // C/D layout (m89-verified): col = lane&15, row = (lane>>4)*4 + reg
  #pragma unroll
  for (int tt = 0; tt < 4; ++tt) {
    #pragma unroll
    for (int r = 0; r < 4; ++r) {
      const int i = w * 16 + grp * 4 + r;
      const int j = tt * 16 + fr;
      if (ATOMIC) {
        atomicAdd(&dst[((size_t)b * CH + i) * CH + j], acc[tt][r]);
      } else {
        float* p = dst + ((size_t)b * (NN / KCHUNK) + chunk) * (CH * CH);
        p[i * CH + j] = acc[tt][r];
      }
    }
  }
}

// Fused reduce(+softmax): block (i, b), thread j. Sums NC_P partials
// (coalesced 256B reads across j), then wave-wide min/sum via shfl_xor.
// softmax(rowmax - e)[j] = exp(minE - e[j]) / sum  (rowmax cancels).
// Writes TRANSPOSED attn_t[b][j][i] for pass-3 broadcast reads.
__global__ __launch_bounds__(64) void k_redsm(const float* __restrict__ partial,
                                              float* __restrict__ attn_t) {
  const int i = blockIdx.x;   // 0..63
  const int b = blockIdx.y;   // 0..15
  const int j = threadIdx.x;  // 0..63
  const float* p = partial + (size_t)b * NC_P * (CH * CH) + i * CH + j;
  float e = 0.0f;
  #pragma unroll 8
  for (int c = 0; c < NC_P; ++c) e += p[(size_t)c * (CH * CH)];
  float mn = e;
  #pragma unroll
  for (int off = 32; off; off >>= 1) mn = fminf(mn, __shfl_xor(mn, off, 64));
  const float v = __expf(mn - e);
  float sum = v;
  #pragma unroll
  for (int off = 32; off; off >>= 1) sum += __shfl_xor(sum, off, 64);
  attn_t[(size_t)b * (CH * CH) + j * CH + i] = v / sum;
}

// Fallback softmax (atomic path): reads dense energy.
__global__ __launch_bounds__(64) void k_softmax(const float* __restrict__ energy,
                                                float* __restrict__ attn_t) {
  const int b = blockIdx.x;
  const int i = threadIdx.x;
  const float* e = energy + ((size_t)b * CH + i) * CH;
  float ev[CH];
  float mn = 3.402823466e38f;
  #pragma unroll
  for (int j = 0; j < CH; ++j) { ev[j] = e[j]; mn = fminf(mn, ev[j]); }
  float sum = 0.0f;
  #pragma unroll
  for (int j = 0; j < CH; ++j) { ev[j] = __expf(mn - ev[j]); sum += ev[j]; }
  const float inv = 1.0f / sum;
  #pragma unroll
  for (int j = 0; j < CH; ++j) attn_t[((size_t)b * CH + j) * CH + i] = ev[j] * inv;
}

// Pass 3: out[b,i,n] = gamma * sum_j attn[i,j] x[b,j,n] + x[b,i,n], all fp32.
__global__ __launch_bounds__(256) void k_out(const float* __restrict__ x,
                                             const float* __restrict__ attn_t,
                                             const float* __restrict__ gamma,
                                             float* __restrict__ out) {
  const int b = blockIdx.y;
  const int n0 = blockIdx.x * NB;
  const int t = threadIdx.x;
  const int w = t >> 6;
  const int lane = t & 63;

  __shared__ __align__(16) float xsh[CH * NB];  // 64 KiB
  __shared__ __align__(16) float ash[CH * CH];  // 16 KiB (attn_t tile)

  const float* xb = x + (size_t)b * CH * NN;
  #pragma unroll
  for (int it = 0; it < 16; ++it) {
    const int flat = it * 256 + t;
    const int row = flat >> 6;
    const int c4 = flat & 63;
    *reinterpret_cast<f32x4*>(&xsh[row * NB + c4 * 4]) =
        *reinterpret_cast<const f32x4*>(xb + (size_t)row * NN + n0 + c4 * 4);
  }
  #pragma unroll
  for (int it = 0; it < 4; ++it) {
    const int flat = it * 256 + t;  // 0..1023 float4s
    *reinterpret_cast<f32x4*>(&ash[flat * 4]) =
        *reinterpret_cast<const f32x4*>(attn_t + (size_t)b * CH * CH + flat * 4);
  }
  const float g = gamma[0];
  __syncthreads();

  f32x4 acc[16] = {};
  #pragma unroll 4
  for (int j = 0; j < CH; ++j) {
    const f32x4 xv = *reinterpret_cast<const f32x4*>(&xsh[j * NB + lane * 4]);
    #pragma unroll
    for (int q = 0; q < 4; ++q) {
      const f32x4 av = *reinterpret_cast<const f32x4*>(&ash[j * CH + w * 16 + q * 4]);
      acc[q * 4 + 0] += av[0] * xv;
      acc[q * 4 + 1] += av[1] * xv;
      acc[q * 4 + 2] += av[2] * xv;
      acc[q * 4 + 3] += av[3] * xv;
    }
  }
  float* ob = out + (size_t)b * CH * NN;
  #pragma unroll
  for (int r = 0; r < 16; ++r) {
    const int i = w * 16 + r;
    const f32x4 xv = *reinterpret_cast<const f32x4*>(&xsh[i * NB + lane * 4]);
    const f32x4 o = g * acc[r] + xv;  // exact fp32 epilogue
    *reinterpret_cast<f32x4*>(ob + (size_t)i * NN + n0 + lane * 4) = o;
  }
}

extern "C" void kernel_launch(void* const* d_in, const int* in_sizes, int n_in,
                              void* d_out, int out_size, void* d_ws, size_t ws_size,
                              hipStream_t stream) {
  const float* x = (const float*)d_in[0];
  const float* gamma = (const float*)d_in[1];
  float* out = (float*)d_out;

  const size_t part_elems = (size_t)BATCH * NC_P * CH * CH;      // 8M floats = 32 MB
  const size_t attn_elems = (size_t)BATCH * CH * CH;             // 64 KiB floats
  const size_t need = (part_elems + attn_elems) * sizeof(float);

  if (ws_size >= need) {
    // Partial-store path: no atomics, 2048 blocks for latency hiding.
    float* partial = (float*)d_ws;
    float* attn_t = partial + part_elems;
    k_energy<KC_P, false><<<dim3(NC_P, BATCH), 256, 0, stream>>>(x, partial);
    k_redsm<<<dim3(CH, BATCH), 64, 0, stream>>>(partial, attn_t);
    k_out<<<dim3(NN / NB, BATCH), 256, 0, stream>>>(x, attn_t, gamma, out);
  } else {
    // Fallback: round-1 proven atomic path (needs only 512 KiB ws).
    float* energy = (float*)d_ws;
    float* attn_t = energy + attn_elems;
    k_zero<<<dim3((BATCH * CH * CH) / 256), 256, 0, stream>>>(energy);
    k_energy<KC_A, true><<<dim3(NC_A, BATCH), 256, 0, stream>>>(x, energy);
    k_softmax<<<dim3(BATCH), 64, 0, stream>>>(energy, attn_t);
    k_out<<<dim3(NN / NB, BATCH), 256, 0, stream>>>(x, attn_t, gamma, out);
  }
}